// Round 11
// baseline (299.400 us; speedup 1.0000x reference)
//
#include <hip/hip_runtime.h>
#include <math.h>

#define Bb 8
#define Nn 64
#define Ff 32
#define Tt 4
#define OUTn 128
#define NPAIR 2016   // 64*63/2 lower-triangle pairs (i>j)

__device__ __forceinline__ float sigmoidf_(float x){ return 1.0f/(1.0f+expf(-x)); }

__device__ __forceinline__ void p2ij(int p, int& i, int& j){
  int ii = (int)((1.0f + sqrtf(1.0f + 8.0f*(float)p)) * 0.5f);
  while (ii*(ii-1)/2 > p) --ii;
  while ((ii+1)*ii/2 <= p) ++ii;
  i = ii; j = p - ii*(ii-1)/2;
}

// sequential-order fp32 dot (bit-identical to the validated round-0 ordering;
// the floor(sigmoid) gate is discontinuous -> this order must not change)
__device__ __forceinline__ float dot32(const float4* __restrict__ u, const float* __restrict__ v){
  const float4* v4 = (const float4*)v;
  float d = 0.f;
#pragma unroll
  for (int q=0;q<8;++q){
    float4 a=u[q], b=v4[q];
    d = fmaf(a.x,b.x,d); d = fmaf(a.y,b.y,d);
    d = fmaf(a.z,b.z,d); d = fmaf(a.w,b.w,d);
  }
  return d;
}

#define VCE(arr,g) ((g&3)==0 ? arr[(g)>>2].x : (g&3)==1 ? arr[(g)>>2].y : \
                    (g&3)==2 ? arr[(g)>>2].z : arr[(g)>>2].w)

// ---- precompute (pair-major): wz/wc[p][b][f], fused t=0 mf0, wbmax, unfmax ----
// (verbatim r9 kernel - validated pass)
__global__ __launch_bounds__(64) void precompute_pair(
    const float* __restrict__ x,
    const float* __restrict__ w_z,
    const float* __restrict__ w_c,
    const float* __restrict__ u_z,
    const float* __restrict__ b_z,
    const float* __restrict__ b_c,
    float* __restrict__ wz,
    float* __restrict__ wc,
    float* __restrict__ mf0,
    float* __restrict__ wbmax,
    float* __restrict__ unfmax) {
  int p = blockIdx.x;
  int i, j; p2ij(p, i, j);
  int l = threadIdx.x, f = l & 31, h = l >> 5;

  __shared__ __align__(16) float xL[Bb][Ff];
  __shared__ __align__(16) float valL[2][Bb][Ff];
  for (int q = l; q < Bb*Ff; q += 64) {
    int b = q >> 5, g = q & 31;
    xL[b][g] = x[(b*Nn + i)*Ff + g];
  }
  __syncthreads();

  const float* W = h ? w_c : w_z;
  const float4* w4 = (const float4*)&W[(((size_t)i*Nn + j)*Ff + f)*Ff];
  float4 wr[8];
#pragma unroll
  for (int q=0;q<8;++q) wr[q]=w4[q];
  float bias = h ? b_c[f] : b_z[f];
  float* dst = h ? wc : wz;
#pragma unroll
  for (int b=0;b<Bb;++b){
    float v = dot32(wr, xL[b]) + bias;
    dst[(size_t)p*256 + b*32 + f] = v;
    valL[h][b][f] = v;
    if (h == 0) {
      float wm = v;
      wm = fmaxf(wm, __shfl_xor(wm,1));  wm = fmaxf(wm, __shfl_xor(wm,2));
      wm = fmaxf(wm, __shfl_xor(wm,4));  wm = fmaxf(wm, __shfl_xor(wm,8));
      wm = fmaxf(wm, __shfl_xor(wm,16));
      if (f == 0) wbmax[p*8 + b] = wm;
    }
  }
  __syncthreads();
  if (h == 0) {
#pragma unroll
    for (int b=0;b<Bb;++b)
      mf0[(size_t)p*256 + b*32 + f] =
          sigmoidf_(valL[0][b][f]) * tanhf(valL[1][b][f]);
  } else {
    const float4* u4 = (const float4*)&u_z[(((size_t)i*Nn + j)*Ff + f)*Ff];
    float ss = 0.f;
#pragma unroll
    for (int q=0;q<8;++q){
      float4 v = u4[q];
      ss = fmaf(v.x,v.x,ss); ss = fmaf(v.y,v.y,ss);
      ss = fmaf(v.z,v.z,ss); ss = fmaf(v.w,v.w,ss);
    }
    ss = fmaxf(ss, __shfl_xor(ss,1));  ss = fmaxf(ss, __shfl_xor(ss,2));
    ss = fmaxf(ss, __shfl_xor(ss,4));  ss = fmaxf(ss, __shfl_xor(ss,8));
    ss = fmaxf(ss, __shfl_xor(ss,16));
    if (f == 0) unfmax[p] = sqrtf(ss);
  }
}

// ---- one MP iteration (t>=1): block=(i, jo); half-wave hw owns j=jo*8+hw,
//      u_z row in regs reused across ALL 8 b (wave-uniform k-loops per bl) ----
__global__ __launch_bounds__(256) void edge_update(
    const float* __restrict__ A,
    const float* __restrict__ u_z,
    const float* __restrict__ u_c,
    const float* __restrict__ wz,
    const float* __restrict__ wc,
    const float* __restrict__ wbmax,
    const float* __restrict__ unfmax,
    const float* __restrict__ mfp,
    float* __restrict__ mfn) {
  int i  = blockIdx.x;   // 64
  int jo = blockIdx.y;   // 8
  if (jo*8 >= i) return; // uniform cull (also kills i==0)
  int tid = threadIdx.x; // 256: staging view (b=tid>>5, f=tid&31)
  int f = tid & 31;
  int sb_ = tid >> 5;    // staging b / j-phase half-wave index (0..7)
  int h32 = tid & 32;

  __shared__ __align__(16) float Mc[Nn][Bb*Ff];   // [k][b*32+f]  64 KB
  __shared__ __align__(16) float aggL[Bb][Ff];
  __shared__ float normC[Nn][Bb];
  __shared__ float nmaxL[Bb];
  __shared__ unsigned long long kadjL[Bb];

  // adjacency masks: wave wv handles b = 2wv, 2wv+1
  {
    int wv = tid >> 6, l = tid & 63;
    float a0 = A[((2*wv    )*Nn + i)*Nn + l];
    float a1 = A[((2*wv + 1)*Nn + i)*Nn + l];
    unsigned long long m0 = __ballot(a0 != 0.0f);
    unsigned long long m1 = __ballot(a1 != 0.0f);
    if (l == 0) { kadjL[2*wv] = m0; kadjL[2*wv+1] = m1; }
  }
  __syncthreads();

  unsigned long long kadjR[Bb];
  unsigned long long kun = 0ull;
#pragma unroll
  for (int b=0;b<Bb;++b){ kadjR[b] = kadjL[b]; kun |= kadjR[b]; }

  // prefetch this half-wave's u_z row (j = jo*8 + hw), hides under staging
  int j = jo*8 + sb_;
  bool jvalid = (j < i);
  int p = i*(i-1)/2 + (jvalid ? j : 0);
  float4 u[8];
  if (jvalid) {
    const float4* u4 = (const float4*)&u_z[(((size_t)i*Nn + j)*Ff + f)*Ff];
#pragma unroll
    for (int q=0;q<8;++q) u[q] = u4[q];
  } else {
#pragma unroll
    for (int q=0;q<8;++q) u[q] = make_float4(0.f,0.f,0.f,0.f);
  }

  // stage M rows (pair-major: 1KB coalesced per k) + per-(k,b) norms for free
  {
    unsigned long long kk = kun;
    int myb = sb_;                       // staging b of this thread
    while (kk) {
      int k = __builtin_ctzll(kk); kk &= kk - 1;
      int hi = i > k ? i : k, lo = i > k ? k : i;
      int pk = hi*(hi-1)/2 + lo;
      if ((kadjR[myb] >> k) & 1ull) {
        float v = mfp[(size_t)pk*256 + tid];
        Mc[k][tid] = v;
        float ss = v*v;
        ss += __shfl_xor(ss,1); ss += __shfl_xor(ss,2); ss += __shfl_xor(ss,4);
        ss += __shfl_xor(ss,8); ss += __shfl_xor(ss,16);
        if (f == 0) normC[k][myb] = sqrtf(ss);
      }
    }
  }
  __syncthreads();

  // agg[b][f]: 4-chain ILP over own-b edges (continuity-safe reorder; gates
  // read Mc bits directly, which are unchanged)
  {
    int myb = sb_;
    unsigned long long kb = kadjR[myb];
    float s0=0.f,s1=0.f,s2=0.f,s3=0.f;
    for (int k = 0; k < Nn; k += 4) {
      if ((kb>>(k  ))&1ull) s0 += Mc[k  ][tid];
      if ((kb>>(k+1))&1ull) s1 += Mc[k+1][tid];
      if ((kb>>(k+2))&1ull) s2 += Mc[k+2][tid];
      if ((kb>>(k+3))&1ull) s3 += Mc[k+3][tid];
    }
    aggL[myb][f] = (s0+s1)+(s2+s3);
  }
  // nmax[b] = max over own edges of row norm
  if (tid < 64) {
    int b = tid >> 3, c = tid & 7;
    unsigned long long kb = kadjL[b];
    float m = 0.f;
#pragma unroll
    for (int q=0;q<8;++q){
      int k = c*8+q;
      if ((kb>>k)&1ull) m = fmaxf(m, normC[k][b]);
    }
    m = fmaxf(m, __shfl_xor(m,1)); m = fmaxf(m, __shfl_xor(m,2));
    m = fmaxf(m, __shfl_xor(m,4));
    if (c == 0) nmaxL[b] = m;
  }
  __syncthreads();

  if (!jvalid) return;   // after all barriers; shuffles below are in-half only

  float unf = unfmax[p];
  float un = 0.f;
#pragma unroll
  for (int q=0;q<8;++q){
    float4 aa = u[q];
    un = fmaf(aa.x,aa.x,un); un = fmaf(aa.y,aa.y,un);
    un = fmaf(aa.z,aa.z,un); un = fmaf(aa.w,aa.w,un);
  }
  un = sqrtf(un);

  for (int bl = 0; bl < Bb; ++bl) {
    unsigned long long kadj = kadjR[bl];
    if (!((kadj >> j) & 1ull)) continue;   // half-uniform
    size_t pb = (size_t)p*256 + bl*32;
    float wb  = wz[pb + f];
    float wcf = wc[pb + f];
    const float* Mj = &Mc[j][bl*32];
    // z = sigmoid(wb + u . (agg - M[i,j]))   (validated fused form)
    {
      const float4* ag4 = (const float4*)aggL[bl];
      const float4* mj4 = (const float4*)Mj;
      float d = 0.f;
#pragma unroll
      for (int q=0;q<8;++q){
        float4 ag = ag4[q], mm = mj4[q];
        float mx = ag.x - mm.x, my = ag.y - mm.y;
        float mz = ag.z - mm.z, mw = ag.w - mm.w;
        d = fmaf(u[q].x,mx,d); d = fmaf(u[q].y,my,d);
        d = fmaf(u[q].z,mz,d); d = fmaf(u[q].w,mw,d);
      }
      float z = sigmoidf_(wb + d);
      float mo = aggL[bl][f] - Mj[f];

      float gs = 0.f;
      float wbm = wbmax[p*8 + bl];
      if (wbm + unf*nmaxL[bl] >= 15.5f) {      // scalar per-(j,b) screen
        unsigned long long kk = kadj;          // wave-uniform mask
        while (kk) {
          int k = __builtin_ctzll(kk); kk &= kk - 1;
          if (k == j) continue;                // half-uniform skip (cheap)
          float nk = normC[k][bl];
          if (wbm + unf*nk < 15.5f) continue;  // scalar per-k screen
          unsigned long long sbb = __ballot(wb + un*nk >= 15.5f);
          if (((sbb >> h32) & 0xFFFFFFFFull) == 0ull) continue;  // per-f screen
          float v = wb + dot32(u, &Mc[k][bl*32]);  // exact gate dot (fixed order)
          if (v >= 16.0f && (v > 17.5f || sigmoidf_(v) >= 1.0f))
            gs += Mc[k][bl*32 + f];
        }
      }

      // rare fire path: u_c dots via in-half shuffles (validated)
      float d2 = 0.f;
      unsigned long long gb = __ballot(gs != 0.0f);
      if (((gb >> h32) & 0xFFFFFFFFull) != 0ull) {
        float4 uc[8];
        const float4* uc4 = (const float4*)&u_c[(((size_t)i*Nn + j)*Ff + f)*Ff];
#pragma unroll
        for (int q=0;q<8;++q) uc[q]=uc4[q];
        float rm = 0.f;
#pragma unroll
        for (int g = 0; g < 32; ++g)
          rm = fmaf(VCE(uc,g), __shfl(gs, h32 + g), rm);
        float dd2 = 0.f;
#pragma unroll
        for (int g = 0; g < 32; ++g)
          dd2 = fmaf(VCE(uc,g), __shfl(rm, h32 + g), dd2);
        d2 = dd2;
      }

      float cur = tanhf(wcf + d2);
      mfn[pb + f] = (1.0f - z)*mo + z*cur;
    }
  }
}

// ---- msg_sum gather + enc = relu(u_node.x + u_msg.msg_sum) (r9, validated) ----
__global__ __launch_bounds__(64) void finalize_enc(
    const float* __restrict__ x,
    const float* __restrict__ A,
    const float* __restrict__ mf,
    const float* __restrict__ u_node,
    const float* __restrict__ u_msg,
    float* __restrict__ enc) {
  int bi = blockIdx.x;
  int b = bi >> 6, i = bi & 63;
  int l = threadIdx.x, f = l & 31, h = l >> 5;

  float a = A[(b*Nn + i)*Nn + l];
  unsigned long long mask = __ballot(a != 0.0f);
  float acc = 0.f;
  unsigned long long mm = mask;
  int idx = 0;
  while (mm) {
    int k = __builtin_ctzll(mm);
    mm &= mm - 1;
    if ((idx & 1) == h) {
      int hi = i > k ? i : k, lo = i > k ? k : i;
      acc += mf[(size_t)(hi*(hi-1)/2 + lo)*256 + b*32 + f];
    }
    idx++;
  }
  float accO = __shfl(acc, l ^ 32);
  acc += accO;

  __shared__ __align__(16) float vecL[2][Ff];
  if (l < 32) { vecL[0][l] = x[(b*Nn + i)*Ff + l]; vecL[1][l] = acc; }
  __syncthreads();
  const float* Urow = (h == 0) ? &u_node[((size_t)i*Ff + f)*Ff]
                               : &u_msg [((size_t)i*Ff + f)*Ff];
  const float4* w4 = (const float4*)Urow;
  float4 w[8];
#pragma unroll
  for (int q=0;q<8;++q) w[q]=w4[q];
  float d = dot32(w, vecL[h]);
  float dO = __shfl(d, l ^ 32);
  if (l < 32) enc[(b*Nn + i)*Ff + f] = fmaxf(d + dO, 0.0f);
}

// ---- output linear + sigmoid: one wave per (b, o) (validated r4) ----
__global__ __launch_bounds__(64) void linear_out(
    const float* __restrict__ enc,
    const float* __restrict__ lin_w,
    const float* __restrict__ lin_b,
    float* __restrict__ out) {
  int b = blockIdx.x >> 7;
  int o = blockIdx.x & 127;
  int l = threadIdx.x;
  const float4* w4 = (const float4*)&lin_w[(size_t)o*(Nn*Ff)];
  const float4* e4 = (const float4*)&enc[(size_t)b*(Nn*Ff)];
  float acc = 0.f;
#pragma unroll
  for (int q = 0; q < 8; ++q) {
    float4 w = w4[q*64 + l], e = e4[q*64 + l];
    acc = fmaf(w.x,e.x,acc); acc = fmaf(w.y,e.y,acc);
    acc = fmaf(w.z,e.z,acc); acc = fmaf(w.w,e.w,acc);
  }
  acc += __shfl_xor(acc, 1);  acc += __shfl_xor(acc, 2);
  acc += __shfl_xor(acc, 4);  acc += __shfl_xor(acc, 8);
  acc += __shfl_xor(acc, 16); acc += __shfl_xor(acc, 32);
  if (l == 0) out[b*OUTn + o] = sigmoidf_(acc + lin_b[o]);
}

extern "C" void kernel_launch(void* const* d_in, const int* in_sizes, int n_in,
                              void* d_out, int out_size, void* d_ws, size_t ws_size,
                              hipStream_t stream) {
  const float* x      = (const float*)d_in[0];
  const float* A      = (const float*)d_in[1];
  const float* w_z    = (const float*)d_in[2];
  const float* w_c    = (const float*)d_in[3];
  const float* u_z    = (const float*)d_in[4];
  const float* u_c    = (const float*)d_in[5];
  const float* b_z    = (const float*)d_in[6];
  const float* b_c    = (const float*)d_in[7];
  const float* u_node = (const float*)d_in[8];
  const float* u_msg  = (const float*)d_in[9];
  const float* lin_w  = (const float*)d_in[10];
  const float* lin_b  = (const float*)d_in[11];
  float* out = (float*)d_out;
  float* ws  = (float*)d_ws;

  const size_t PB = (size_t)NPAIR * 256;      // 516096 floats
  float* wz     = ws;
  float* wc     = wz   + PB;
  float* mf0    = wc   + PB;
  float* mf1    = mf0  + PB;
  float* wbmax  = mf1  + PB;                  // NPAIR*8
  float* unfmax = wbmax + (size_t)NPAIR*8;    // NPAIR
  float* enc    = unfmax + NPAIR;             // 8*64*32

  precompute_pair<<<NPAIR, 64, 0, stream>>>(x, w_z, w_c, u_z, b_z, b_c,
                                            wz, wc, mf0, wbmax, unfmax);

  const float* mfR = mf0; float* mfW = mf1;
  for (int t = 1; t < Tt; ++t) {
    edge_update<<<dim3(Nn, 8), 256, 0, stream>>>(A, u_z, u_c, wz, wc,
                                                 wbmax, unfmax, mfR, mfW);
    float* tm = (float*)mfR; mfR = mfW; mfW = tm;
  }
  finalize_enc<<<Bb*Nn, 64, 0, stream>>>(x, A, mfR, u_node, u_msg, enc);
  linear_out<<<Bb*OUTn, 64, 0, stream>>>(enc, lin_w, lin_b, out);
}

// Round 12
// 144.876 us; speedup vs baseline: 2.0666x; 2.0666x over previous
//
#include <hip/hip_runtime.h>
#include <math.h>

#define Bb 8
#define Nn 64
#define Ff 32
#define Tt 4
#define OUTn 128
#define NPAIR 2016   // 64*63/2 lower-triangle pairs (i>j)

__device__ __forceinline__ float sigmoidf_(float x){ return 1.0f/(1.0f+expf(-x)); }

__device__ __forceinline__ void p2ij(int p, int& i, int& j){
  int ii = (int)((1.0f + sqrtf(1.0f + 8.0f*(float)p)) * 0.5f);
  while (ii*(ii-1)/2 > p) --ii;
  while ((ii+1)*ii/2 <= p) ++ii;
  i = ii; j = p - ii*(ii-1)/2;
}

// sequential-order fp32 dot (bit-identical to the validated round-0 ordering;
// the floor(sigmoid) gate is discontinuous -> this order must not change)
__device__ __forceinline__ float dot32(const float4* __restrict__ u, const float* __restrict__ v){
  const float4* v4 = (const float4*)v;
  float d = 0.f;
#pragma unroll
  for (int q=0;q<8;++q){
    float4 a=u[q], b=v4[q];
    d = fmaf(a.x,b.x,d); d = fmaf(a.y,b.y,d);
    d = fmaf(a.z,b.z,d); d = fmaf(a.w,b.w,d);
  }
  return d;
}

// ---- precompute wzxb/wcxb for lower-tri pairs + fused t=0 update ----
// (verbatim from the 141-us build)
__global__ __launch_bounds__(64) void precompute_pair(
    const float* __restrict__ x,
    const float* __restrict__ w_z,
    const float* __restrict__ w_c,
    const float* __restrict__ b_z,
    const float* __restrict__ b_c,
    float* __restrict__ wzxb,
    float* __restrict__ wcxb,
    float* __restrict__ mf0) {
  int p = blockIdx.x;
  int i, j; p2ij(p, i, j);
  int l = threadIdx.x, f = l & 31, h = l >> 5;

  __shared__ __align__(16) float xL[Bb][Ff];
  __shared__ __align__(16) float valL[2][Bb][Ff];
  for (int q = l; q < Bb*Ff; q += 64) {
    int b = q >> 5, g = q & 31;
    xL[b][g] = x[(b*Nn + i)*Ff + g];
  }
  __syncthreads();

  const float* W = h ? w_c : w_z;
  const float4* w4 = (const float4*)&W[(((size_t)i*Nn + j)*Ff + f)*Ff];
  float4 w[8];
#pragma unroll
  for (int q=0;q<8;++q) w[q]=w4[q];
  float bias = h ? b_c[f] : b_z[f];
  float* dst = h ? wcxb : wzxb;
#pragma unroll
  for (int b=0;b<Bb;++b){
    float v = dot32(w, xL[b]) + bias;
    dst[((size_t)(b*Nn + i)*Nn + j)*Ff + f] = v;
    valL[h][b][f] = v;
  }
  __syncthreads();
  if (h == 0) {
#pragma unroll
    for (int b=0;b<Bb;++b){
      mf0[((size_t)(b*Nn + i)*Nn + j)*Ff + f] =
          sigmoidf_(valL[0][b][f]) * tanhf(valL[1][b][f]);
    }
  }
}

// ---- one MP iteration (t>=1); block=(b,i,jh) via XCD-locality swizzle ----
// flat%8 == (2i+jh)&7 independent of b -> all 8 b-blocks of one (i,jh) land
// on the same XCD, so each u_z row fills exactly one L2 per iteration.
__global__ __launch_bounds__(256) void edge_update(
    const float* __restrict__ A,
    const float* __restrict__ u_z,
    const float* __restrict__ u_c,
    const float* __restrict__ wzxb,
    const float* __restrict__ wcxb,
    const float* __restrict__ mfp,
    float* __restrict__ mfn) {
  int flat = blockIdx.x;          // 0..1023
  int r8 = flat & 7, qd = flat >> 3;
  int b    = qd >> 4;             // 0..7
  int code = (qd & 15)*8 + r8;    // 2i+jh, 0..127
  int i  = code >> 1;
  int jh = code & 1;
  int tid = threadIdx.x;

  __shared__ __align__(16) float Mc [Nn][Ff];
  __shared__ __align__(16) float moL[32][Ff];
  __shared__ __align__(16) float gsL[32][Ff];
  __shared__ __align__(16) float rmL[32][Ff];
  __shared__ float aggL[Ff];
  __shared__ float normL[Nn];
  __shared__ float nmaxS;
  __shared__ int nbrL[Nn];
  __shared__ int jlistL[32], jslotL[32];
  __shared__ int nnL, jcL;

  if (tid < 64) {
    float a = A[(b*Nn + i)*Nn + tid];
    bool e = (a != 0.0f);
    unsigned long long m = __ballot(e);
    if (e) nbrL[__popcll(m & ((1ull << tid) - 1ull))] = tid;
    bool ej = e && (tid < i);
    unsigned long long mj = __ballot(ej);
    if (ej) {
      int r = __popcll(mj & ((1ull << tid) - 1ull));
      if ((r & 1) == jh) {
        int jl = r >> 1;
        jlistL[jl] = tid;
        jslotL[jl] = __popcll(m & ((1ull << tid) - 1ull));
      }
    }
    if (tid == 0) {
      nnL = __popcll(m);
      jcL = (__popcll(mj) + 1 - jh) >> 1;
    }
  }
  __syncthreads();
  int nn = nnL, jc = jcL;
  if (jc == 0) return;
  int P = jc * Ff;

  // prefetch round-0 operands; latency hides under Mc staging + agg/nmax
  bool act0 = tid < P;
  int jl0 = act0 ? (tid >> 5) : 0;
  int f0 = tid & 31;
  int j0 = jlistL[jl0];
  int jslot0 = jslotL[jl0];
  size_t eoff0 = ((size_t)(b*Nn + i)*Nn + j0)*Ff + f0;
  float4 u0[8];
  float wb0 = -1.0e30f;
  if (act0) {
    const float4* u4 = (const float4*)&u_z[(((size_t)i*Nn + j0)*Ff + f0)*Ff];
#pragma unroll
    for (int q=0;q<8;++q) u0[q] = u4[q];
    wb0 = wzxb[eoff0];
  } else {
#pragma unroll
    for (int q=0;q<8;++q) u0[q] = make_float4(0.f,0.f,0.f,0.f);
  }

  // stage compact M rows; per-row norms for free via half-wave shuffles
  for (int qq = tid; qq < nn*Ff; qq += 256) {
    int s = qq >> 5, ff = qq & 31;
    int k = nbrL[s];
    int hi = i > k ? i : k, lo = i > k ? k : i;
    float v = mfp[((size_t)(b*Nn + hi)*Nn + lo)*Ff + ff];
    Mc[s][ff] = v;
    float ss = v*v;
    ss += __shfl_xor(ss,1); ss += __shfl_xor(ss,2); ss += __shfl_xor(ss,4);
    ss += __shfl_xor(ss,8); ss += __shfl_xor(ss,16);
    if (ff == 0) normL[s] = sqrtf(ss);
  }
  __syncthreads();
  // agg: ascending-k serial chain (reference order) in wave0 lanes 0..31;
  // nmax tree in wave1 (lanes 64..127) concurrently
  if (tid < Ff) {
    float sAcc = 0.f;
    for (int s = 0; s < nn; ++s) sAcc += Mc[s][tid];
    aggL[tid] = sAcc;
  }
  if (tid >= 64 && tid < 128) {
    int s = tid - 64;
    float nv = (s < nn) ? normL[s] : 0.f;
    nv = fmaxf(nv, __shfl_xor(nv,1));  nv = fmaxf(nv, __shfl_xor(nv,2));
    nv = fmaxf(nv, __shfl_xor(nv,4));  nv = fmaxf(nv, __shfl_xor(nv,8));
    nv = fmaxf(nv, __shfl_xor(nv,16)); nv = fmaxf(nv, __shfl_xor(nv,32));
    if (s == 0) nmaxS = nv;
  }
  __syncthreads();
  for (int qq = tid; qq < P; qq += 256) {
    int jl = qq >> 5, ff = qq & 31;
    moL[jl][ff] = aggL[ff] - Mc[jslotL[jl]][ff];
  }
  __syncthreads();
  float nmax = nmaxS;

  int NR = (P + 255) >> 8;
  for (int r = 0; r < NR; ++r) {
    int p = tid + (r << 8);
    bool act = p < P;
    int jl, f, j, jslot; size_t eoff;
    float4 u[8]; float wb;
    if (r == 0) {
      jl = jl0; f = f0; j = j0; jslot = jslot0; eoff = eoff0; wb = wb0;
#pragma unroll
      for (int q=0;q<8;++q) u[q] = u0[q];
    } else {
      jl = act ? (p >> 5) : 0;
      f = p & 31;
      j = jlistL[jl]; jslot = jslotL[jl];
      eoff = ((size_t)(b*Nn + i)*Nn + j)*Ff + f;
      wb = -1.0e30f;
      if (act) {
        const float4* u4 = (const float4*)&u_z[(((size_t)i*Nn + j)*Ff + f)*Ff];
#pragma unroll
        for (int q=0;q<8;++q) u[q] = u4[q];
        wb = wzxb[eoff];
      } else {
#pragma unroll
        for (int q=0;q<8;++q) u[q] = make_float4(0.f,0.f,0.f,0.f);
      }
    }

    float un = 0.f;
#pragma unroll
    for (int q=0;q<8;++q){
      float4 aa=u[q];
      un = fmaf(aa.x,aa.x,un); un = fmaf(aa.y,aa.y,un);
      un = fmaf(aa.z,aa.z,un); un = fmaf(aa.w,aa.w,un);
    }
    un = sqrtf(un);

    float z = 0.f;
    if (act) z = sigmoidf_(wb + dot32(u, moL[jl]));

    // half-wave scalar screens: conservative superset of the validated
    // per-(f,k) Cauchy-Schwarz screen; survivors run the exact gate test.
    float wbm = wb;
    wbm = fmaxf(wbm, __shfl_xor(wbm,1));  wbm = fmaxf(wbm, __shfl_xor(wbm,2));
    wbm = fmaxf(wbm, __shfl_xor(wbm,4));  wbm = fmaxf(wbm, __shfl_xor(wbm,8));
    wbm = fmaxf(wbm, __shfl_xor(wbm,16));
    float unm = un;
    unm = fmaxf(unm, __shfl_xor(unm,1));  unm = fmaxf(unm, __shfl_xor(unm,2));
    unm = fmaxf(unm, __shfl_xor(unm,4));  unm = fmaxf(unm, __shfl_xor(unm,8));
    unm = fmaxf(unm, __shfl_xor(unm,16));

    float gs = 0.f;
    if (act && (wbm + unm*nmax >= 15.5f)) {     // per-j scalar screen
      for (int s = 0; s < nn; ++s) {
        if (s == jslot) continue;
        if (wbm + unm*normL[s] < 15.5f) continue;  // per-k scalar screen
        float v = wb + dot32(u, Mc[s]);            // exact gate dot (fixed order)
        if (v >= 16.0f && (v > 17.5f || sigmoidf_(v) >= 1.0f)) gs += Mc[s][f];
      }
    }
    if (act) gsL[jl][f] = gs;

    // rare fire path: intra-wave LDS RAW (no barriers needed)
    unsigned long long bal = __ballot(act && gs != 0.0f);
    bool rowfire = ((bal >> (tid & 32)) & 0xFFFFFFFFull) != 0ull;
    float4 uc[8]; float d2 = 0.f;
    if (act && rowfire) {
      const float4* uc4 = (const float4*)&u_c[(((size_t)i*Nn + j)*Ff + f)*Ff];
#pragma unroll
      for (int q=0;q<8;++q) uc[q]=uc4[q];
      rmL[jl][f] = dot32(uc, gsL[jl]);
    }
    if (act && rowfire) d2 = dot32(uc, rmL[jl]);

    if (act) {
      float cur = tanhf(wcxb[eoff] + d2);
      mfn[eoff] = (1.0f - z)*moL[jl][f] + z*cur;
    }
  }
}

// ---- msg_sum gather + enc = relu(u_node.x + u_msg.msg_sum) (141-us build) ----
__global__ __launch_bounds__(64) void finalize_enc(
    const float* __restrict__ x,
    const float* __restrict__ A,
    const float* __restrict__ mf,
    const float* __restrict__ u_node,
    const float* __restrict__ u_msg,
    float* __restrict__ enc) {
  int bi = blockIdx.x;
  int b = bi >> 6, i = bi & 63;
  int l = threadIdx.x, f = l & 31, h = l >> 5;

  float a = A[(b*Nn + i)*Nn + l];
  unsigned long long mask = __ballot(a != 0.0f);
  float acc = 0.f;
  unsigned long long mm = mask;
  int idx = 0;
  while (mm) {
    int k = __builtin_ctzll(mm);
    mm &= mm - 1;
    if ((idx & 1) == h) {
      int hi = i > k ? i : k, lo = i > k ? k : i;
      acc += mf[((size_t)(b*Nn + hi)*Nn + lo)*Ff + f];
    }
    idx++;
  }
  float accO = __shfl(acc, l ^ 32);
  acc += accO;

  __shared__ __align__(16) float vecL[2][Ff];
  if (l < 32) { vecL[0][l] = x[(b*Nn + i)*Ff + l]; vecL[1][l] = acc; }
  __syncthreads();
  const float* Urow = (h == 0) ? &u_node[((size_t)i*Ff + f)*Ff]
                               : &u_msg [((size_t)i*Ff + f)*Ff];
  const float4* w4 = (const float4*)Urow;
  float4 w[8];
#pragma unroll
  for (int q=0;q<8;++q) w[q]=w4[q];
  float d = dot32(w, vecL[h]);
  float dO = __shfl(d, l ^ 32);
  if (l < 32) enc[(b*Nn + i)*Ff + f] = fmaxf(d + dO, 0.0f);
}

// ---- output linear + sigmoid: one wave per (b, o) (141-us build) ----
__global__ __launch_bounds__(64) void linear_out(
    const float* __restrict__ enc,
    const float* __restrict__ lin_w,
    const float* __restrict__ lin_b,
    float* __restrict__ out) {
  int b = blockIdx.x >> 7;
  int o = blockIdx.x & 127;
  int l = threadIdx.x;
  const float4* w4 = (const float4*)&lin_w[(size_t)o*(Nn*Ff)];
  const float4* e4 = (const float4*)&enc[(size_t)b*(Nn*Ff)];
  float acc = 0.f;
#pragma unroll
  for (int q = 0; q < 8; ++q) {
    float4 w = w4[q*64 + l], e = e4[q*64 + l];
    acc = fmaf(w.x,e.x,acc); acc = fmaf(w.y,e.y,acc);
    acc = fmaf(w.z,e.z,acc); acc = fmaf(w.w,e.w,acc);
  }
  acc += __shfl_xor(acc, 1);  acc += __shfl_xor(acc, 2);
  acc += __shfl_xor(acc, 4);  acc += __shfl_xor(acc, 8);
  acc += __shfl_xor(acc, 16); acc += __shfl_xor(acc, 32);
  if (l == 0) out[b*OUTn + o] = sigmoidf_(acc + lin_b[o]);
}

extern "C" void kernel_launch(void* const* d_in, const int* in_sizes, int n_in,
                              void* d_out, int out_size, void* d_ws, size_t ws_size,
                              hipStream_t stream) {
  const float* x      = (const float*)d_in[0];
  const float* A      = (const float*)d_in[1];
  const float* w_z    = (const float*)d_in[2];
  const float* w_c    = (const float*)d_in[3];
  const float* u_z    = (const float*)d_in[4];
  const float* u_c    = (const float*)d_in[5];
  const float* b_z    = (const float*)d_in[6];
  const float* b_c    = (const float*)d_in[7];
  const float* u_node = (const float*)d_in[8];
  const float* u_msg  = (const float*)d_in[9];
  const float* lin_w  = (const float*)d_in[10];
  const float* lin_b  = (const float*)d_in[11];
  float* out = (float*)d_out;
  float* ws  = (float*)d_ws;

  const size_t SZ = (size_t)Bb*Nn*Nn*Ff;  // 1,048,576 floats
  float* wzxb = ws;
  float* wcxb = ws + SZ;
  float* mf0  = ws + 2*SZ;
  float* mf1  = ws + 3*SZ;
  float* enc  = ws + 4*SZ;

  // t=0 fused into precompute
  precompute_pair<<<NPAIR, 64, 0, stream>>>(x, w_z, w_c, b_z, b_c,
                                            wzxb, wcxb, mf0);

  const float* rd = mf0; float* wr = mf1;
  for (int t = 1; t < Tt; ++t) {
    edge_update<<<Bb*Nn*2, 256, 0, stream>>>(A, u_z, u_c, wzxb, wcxb, rd, wr);
    float* tmp = (float*)rd; rd = wr; wr = tmp;
  }
  finalize_enc<<<Bb*Nn, 64, 0, stream>>>(x, A, rd, u_node, u_msg, enc);
  linear_out<<<Bb*OUTn, 64, 0, stream>>>(enc, lin_w, lin_b, out);
}